// Round 7
// baseline (235.411 us; speedup 1.0000x reference)
//
#include <hip/hip_runtime.h>
#include <math.h>

#define BB 2
#define CC 64
#define NN 4096
#define NBLK 512
#define SCALE 0.35355339059327373f  // 1/sqrt(8)

typedef _Float16 f16x8 __attribute__((ext_vector_type(8)));
typedef _Float16 f16x4 __attribute__((ext_vector_type(4)));
typedef float f32x4 __attribute__((ext_vector_type(4)));

union H2U { _Float16 h; unsigned short u; };
static __device__ inline unsigned short f2h_bits(float f) {
    H2U c; c.h = (_Float16)f; return c.u;
}

// ---------------------------------------------------------------------------
// Single fused kernel, grid = 512 blocks x 512 thr (= exactly 2 blocks/CU,
// co-resident by __launch_bounds__(512,4): VGPR<=128, LDS ~41KB).
//
// Phase 1: (a) all threads convert x -> xh f16 [b][c][n] (2 elems each);
//          (b) blocks 0..15: q,k projections (1 thread = 1 position),
//              qh[b][n][8] (SCALE folded), kh[b][n][8].
// Grid barrier: device-scope atomic counter (ctr zeroed by captured memset).
// Phase 2: flash attention (verified R5/R6 path: swapped QK^T, lane-local
//          softmax, 8-shfl P redistribution), but PV accumulates
//          Z = X * P^T  (A-operand = raw xh rows) instead of V*P^T.
// Epilogue: cross-wave merge of (m,l,Z) in LDS -> normalized zm[c'][q],
//          then out[c,q] = x + gamma * (Wv . zm[:,q])  -- the v-projection
//          algebraically moved after the attention reduction.
// ---------------------------------------------------------------------------
__global__ __launch_bounds__(512, 4) void fused_kernel(
    const float* __restrict__ x, const float* __restrict__ Wq,
    const float* __restrict__ Wk, const float* __restrict__ Wv,
    const float* __restrict__ gamma, float* __restrict__ out,
    unsigned* __restrict__ ctr, _Float16* __restrict__ qh,
    _Float16* __restrict__ kh, _Float16* __restrict__ xh)
{
    const int tid = (int)threadIdx.x;
    const int bid = (int)blockIdx.x;
    const int gt = bid * 512 + tid;                 // 0..262143

    __shared__ float sm_acc[8 * 64 * 17];           // 34816 B (stride-17 pad)
    __shared__ float sm_m[8][16];
    __shared__ float sm_l[8][16];
    __shared__ float zm[64][16];                    // merged, normalized Z

    // ---------------- Phase 1a: x -> f16 (xh[b][c][n]) ----------------
    {
        const float2 v = ((const float2*)x)[gt];    // 262144*2 = |x| exactly
        ushort2 h; h.x = f2h_bits(v.x); h.y = f2h_bits(v.y);
        ((ushort2*)xh)[gt] = h;
    }
    // ---------------- Phase 1b: q,k projections ----------------
    if (gt < BB * NN) {                             // blocks 0..15 only
        const int b = gt >> 12;
        const int n = gt & (NN - 1);
        const float* xp = x + (size_t)b * CC * NN + n;
        float xc[CC];
#pragma unroll
        for (int c = 0; c < CC; ++c) xc[c] = xp[(size_t)c * NN];
        float aq[8], ak[8];
#pragma unroll
        for (int r = 0; r < 8; ++r) { aq[r] = 0.f; ak[r] = 0.f; }
#pragma unroll
        for (int c = 0; c < CC; ++c) {
            const float xv = xc[c];
#pragma unroll
            for (int r = 0; r < 8; ++r) {
                aq[r] = fmaf(Wq[r * CC + c], xv, aq[r]);
                ak[r] = fmaf(Wk[r * CC + c], xv, ak[r]);
            }
        }
        f16x8 oq, ok;
#pragma unroll
        for (int r = 0; r < 8; ++r) {
            oq[r] = (_Float16)(aq[r] * SCALE);
            ok[r] = (_Float16)ak[r];
        }
        *(f16x8*)(qh + (size_t)gt * 8) = oq;
        *(f16x8*)(kh + (size_t)gt * 8) = ok;
    }

    // ---------------- Grid barrier (all 512 blocks co-resident) ----------
    __threadfence();
    __syncthreads();
    if (tid == 0) {
        atomicAdd(ctr, 1u);
        int guard = 0;
        while (__hip_atomic_load(ctr, __ATOMIC_ACQUIRE,
                                 __HIP_MEMORY_SCOPE_AGENT) < (unsigned)NBLK &&
               guard < (1 << 20)) {
            __builtin_amdgcn_s_sleep(8);
            ++guard;
        }
    }
    __syncthreads();

    // ---------------- Phase 2: flash attention (Z = X * P^T) -------------
    const int wid = tid >> 6;                      // 0..7 = K-split slice
    const int lane = tid & 63;
    const int lg = lane >> 4;                      // 0..3
    const int lc = lane & 15;                      // 0..15
    const int b  = bid & 1;
    const int qi = bid >> 1;                       // 0..255
    const int q0 = qi * 16;

    const f16x8 zf = {};
    const f32x4 z4 = {};

    f16x8 qfrag = zf;
    if (lg == 0)
        qfrag = *(const f16x8*)(qh + ((size_t)b * NN + q0 + lc) * 8);

    float m = -1e30f, l = 0.f;
    f32x4 acc0 = z4, acc1 = z4, acc2 = z4, acc3 = z4;

    const _Float16* khb = kh + (size_t)b * NN * 8;
    const _Float16* xhb = xh + (size_t)b * CC * NN;   // f16 [c][n]
    const int kbase = wid * 512;

#pragma unroll 4
    for (int ch = 0; ch < 16; ++ch) {
        const int k0 = kbase + ch * 32;

        // QK^T: D[k][q] for 2 k-tiles of 16
        f16x8 kf0 = zf, kf1 = zf;
        if (lg == 0) {
            kf0 = *(const f16x8*)(khb + (size_t)(k0 + lc) * 8);
            kf1 = *(const f16x8*)(khb + (size_t)(k0 + 16 + lc) * 8);
        }
        // X fragments (rows c = ct*16+lc, k = k0 + lg*8 + j), 16B contiguous
        const _Float16* xg = xhb + (size_t)k0 + lg * 8;
        f16x8 v0 = *(const f16x8*)(xg + (size_t)(0 * 16 + lc) * NN);
        f16x8 v1 = *(const f16x8*)(xg + (size_t)(1 * 16 + lc) * NN);
        f16x8 v2 = *(const f16x8*)(xg + (size_t)(2 * 16 + lc) * NN);
        f16x8 v3 = *(const f16x8*)(xg + (size_t)(3 * 16 + lc) * NN);

        __builtin_amdgcn_s_setprio(1);
        f32x4 s0 = __builtin_amdgcn_mfma_f32_16x16x32_f16(kf0, qfrag, z4, 0, 0, 0);
        f32x4 s1 = __builtin_amdgcn_mfma_f32_16x16x32_f16(kf1, qfrag, z4, 0, 0, 0);
        __builtin_amdgcn_s_setprio(0);

        // chunk max for my q (= lc); k-rows live across lg -> xor 16, 32
        float cm = fmaxf(fmaxf(fmaxf(s0[0], s0[1]), fmaxf(s0[2], s0[3])),
                         fmaxf(fmaxf(s1[0], s1[1]), fmaxf(s1[2], s1[3])));
        cm = fmaxf(cm, __shfl_xor(cm, 16));
        cm = fmaxf(cm, __shfl_xor(cm, 32));

        if (!__all(cm <= m)) {                     // deferred-max (THR=0)
            const float mnew = fmaxf(m, cm);
            const float alpha = __expf(m - mnew);
            m = mnew;
            l *= alpha;
            acc0 *= alpha; acc1 *= alpha; acc2 *= alpha; acc3 *= alpha;
        }

        float pr[8];
        float ls = 0.f;
#pragma unroll
        for (int v = 0; v < 4; ++v) { pr[v]     = __expf(s0[v] - m); ls += pr[v]; }
#pragma unroll
        for (int v = 0; v < 4; ++v) { pr[4 + v] = __expf(s1[v] - m); ls += pr[4 + v]; }
        ls += __shfl_xor(ls, 16);
        ls += __shfl_xor(ls, 32);
        l += ls;

        // pack P to f16, redistribute to PV B-fragment layout (verified R5):
        // target lane (lg,lc) needs P[kk=lg*8+j][q=lc].
        union { f16x4 h; unsigned u[2]; } P0, P1;
#pragma unroll
        for (int v = 0; v < 4; ++v) {
            P0.h[v] = (_Float16)pr[v];
            P1.h[v] = (_Float16)pr[4 + v];
        }
        const int sA = (((2 * lg) & 3) << 4) + lc;
        const int sB = (((2 * lg + 1) & 3) << 4) + lc;
        const unsigned t00 = __shfl(P0.u[0], sA), t01 = __shfl(P0.u[1], sA);
        const unsigned t10 = __shfl(P1.u[0], sA), t11 = __shfl(P1.u[1], sA);
        const unsigned u00 = __shfl(P0.u[0], sB), u01 = __shfl(P0.u[1], sB);
        const unsigned u10 = __shfl(P1.u[0], sB), u11 = __shfl(P1.u[1], sB);
        const bool hi = (lg & 2) != 0;
        union { unsigned u[4]; f16x8 v; } PF;
        PF.u[0] = hi ? t10 : t00;
        PF.u[1] = hi ? t11 : t01;
        PF.u[2] = hi ? u10 : u00;
        PF.u[3] = hi ? u11 : u01;

        // Z accumulate: acc[ct] += X[c][k] * P[k][q]
        __builtin_amdgcn_s_setprio(1);
        acc0 = __builtin_amdgcn_mfma_f32_16x16x32_f16(v0, PF.v, acc0, 0, 0, 0);
        acc1 = __builtin_amdgcn_mfma_f32_16x16x32_f16(v1, PF.v, acc1, 0, 0, 0);
        acc2 = __builtin_amdgcn_mfma_f32_16x16x32_f16(v2, PF.v, acc2, 0, 0, 0);
        acc3 = __builtin_amdgcn_mfma_f32_16x16x32_f16(v3, PF.v, acc3, 0, 0, 0);
        __builtin_amdgcn_s_setprio(0);
    }

    // ---- per-wave partials -> LDS ----
    if (lane < 16) { sm_m[wid][lc] = m; sm_l[wid][lc] = l; }
    {
        float* sa = sm_acc + (size_t)wid * 64 * 17 + lc;
#pragma unroll
        for (int v = 0; v < 4; ++v) {
            sa[(0 * 16 + lg * 4 + v) * 17] = acc0[v];
            sa[(1 * 16 + lg * 4 + v) * 17] = acc1[v];
            sa[(2 * 16 + lg * 4 + v) * 17] = acc2[v];
            sa[(3 * 16 + lg * 4 + v) * 17] = acc3[v];
        }
    }
    __syncthreads();

    // ---- 8-way merge -> normalized zm[c'][q] ----
    {
        const int c = tid >> 3;                    // 0..63
        const int q2 = (tid & 7) * 2;
#pragma unroll
        for (int dq = 0; dq < 2; ++dq) {
            const int q = q2 + dq;
            float M = sm_m[0][q];
#pragma unroll
            for (int w = 1; w < 8; ++w) M = fmaxf(M, sm_m[w][q]);
            float L = 0.f, O = 0.f;
#pragma unroll
            for (int w = 0; w < 8; ++w) {
                const float e = __expf(sm_m[w][q] - M);
                L = fmaf(sm_l[w][q], e, L);
                O = fmaf(sm_acc[(w * 64 + c) * 17 + q], e, O);
            }
            zm[c][q] = O / L;
        }
    }
    __syncthreads();

    // ---- Wv epilogue + residual: out[c][q] = x + g * (Wv . zm[:,q]) ----
    {
        const int c = tid >> 3;                    // 0..63
        const int q2 = (tid & 7) * 2;
        const float* wr = Wv + c * 64;
        float o0 = 0.f, o1 = 0.f;
#pragma unroll
        for (int cc = 0; cc < 64; ++cc) {
            const float wv = wr[cc];
            o0 = fmaf(wv, zm[cc][q2],     o0);
            o1 = fmaf(wv, zm[cc][q2 + 1], o1);
        }
        const float g = gamma[0];
        const size_t oi = (size_t)b * CC * NN + (size_t)c * NN + q0 + q2;
        out[oi]     = fmaf(g, o0, x[oi]);
        out[oi + 1] = fmaf(g, o1, x[oi + 1]);
    }
}

// ---------------------------------------------------------------------------
extern "C" void kernel_launch(void* const* d_in, const int* in_sizes, int n_in,
                              void* d_out, int out_size, void* d_ws, size_t ws_size,
                              hipStream_t stream)
{
    const float* x     = (const float*)d_in[0];
    const float* Wq    = (const float*)d_in[1];
    const float* Wk    = (const float*)d_in[2];
    const float* Wv    = (const float*)d_in[3];
    const float* gamma = (const float*)d_in[4];
    float* out = (float*)d_out;

    // ws layout: ctr (256 B slot) | qh 128K | kh 128K | xh 1M
    char* ws = (char*)d_ws;
    unsigned* ctr = (unsigned*)ws;
    _Float16* qh = (_Float16*)(ws + 256);
    _Float16* kh = qh + (size_t)BB * NN * 8;
    _Float16* xh = kh + (size_t)BB * NN * 8;

    hipMemsetAsync(ctr, 0, 4, stream);             // zero the barrier counter
    hipLaunchKernelGGL(fused_kernel, dim3(NBLK), dim3(512), 0, stream,
                       x, Wq, Wk, Wv, gamma, out, ctr, qh, kh, xh);
}

// Round 8
// 87.889 us; speedup vs baseline: 2.6785x; 2.6785x over previous
//
#include <hip/hip_runtime.h>
#include <math.h>

#define BB 2
#define CC 64
#define NN 4096
#define SCALE 0.35355339059327373f  // 1/sqrt(8)
#define DEFER_THR 8.0f

typedef _Float16 f16x8 __attribute__((ext_vector_type(8)));
typedef _Float16 f16x4 __attribute__((ext_vector_type(4)));
typedef float f32x4 __attribute__((ext_vector_type(4)));
typedef float f32x4v __attribute__((ext_vector_type(4)));

// ---------------------------------------------------------------------------
// Kernel 1: q/k projections + f16 pack of x.
//   t <  8192 : q position t          -> qh[b][n][8] (SCALE folded)
//   t < 16384 : k position t-8192     -> kh[b][n][8]
//   else      : pack pt = t-16384     -> xp[b][n/8][c][n%8] = f16(x)
//               pt = b*32768 + g*64 + c ; dst f16x8 index == pt (coalesced)
// ---------------------------------------------------------------------------
__global__ __launch_bounds__(256) void proj_kernel(
    const float* __restrict__ x, const float* __restrict__ Wq,
    const float* __restrict__ Wk, _Float16* __restrict__ qh,
    _Float16* __restrict__ kh, _Float16* __restrict__ xp)
{
    const int t = (int)blockIdx.x * 256 + (int)threadIdx.x;   // 0..81919

    if (t < 16384) {
        const int grp = t >> 13;                              // 0=q, 1=k
        const int p = t & 8191;
        const int b = p >> 12;
        const int n = p & (NN - 1);
        const float* xc0 = x + (size_t)b * CC * NN + n;
        float xc[CC];
#pragma unroll
        for (int c = 0; c < CC; ++c) xc[c] = xc0[(size_t)c * NN];

        const float* W = (grp == 0) ? Wq : Wk;
        float a[8];
#pragma unroll
        for (int j = 0; j < 8; ++j) a[j] = 0.f;
#pragma unroll
        for (int c = 0; c < CC; ++c) {
            const float xv = xc[c];
#pragma unroll
            for (int j = 0; j < 8; ++j)
                a[j] = fmaf(W[j * CC + c], xv, a[j]);
        }
        f16x8 o;
        if (grp == 0) {
#pragma unroll
            for (int j = 0; j < 8; ++j) o[j] = (_Float16)(a[j] * SCALE);
            *(f16x8*)(qh + (size_t)p * 8) = o;
        } else {
#pragma unroll
            for (int j = 0; j < 8; ++j) o[j] = (_Float16)a[j];
            *(f16x8*)(kh + (size_t)p * 8) = o;
        }
    } else {
        const int pt = t - 16384;                             // 0..65535
        const int b = pt >> 15;
        const int g = (pt >> 6) & 511;
        const int c = pt & 63;
        const float* src = x + ((size_t)(b * CC + c) * NN + g * 8);
        const float4 a0 = *(const float4*)(src);
        const float4 a1 = *(const float4*)(src + 4);
        f16x8 o;
        o[0] = (_Float16)a0.x; o[1] = (_Float16)a0.y;
        o[2] = (_Float16)a0.z; o[3] = (_Float16)a0.w;
        o[4] = (_Float16)a1.x; o[5] = (_Float16)a1.y;
        o[6] = (_Float16)a1.z; o[7] = (_Float16)a1.w;
        ((f16x8*)xp)[pt] = o;                                 // coalesced
    }
}

// verified 8-shfl redistribution: from per-lane scores p8[0..7] of two
// 16-key tiles (even regs = tile A rows lg*4+v, odd = tile B) to the PV
// B-fragment: lane (lg,lc) <- P[k = lg*8+j][q = lc], j = 0..7.
static __device__ inline f16x8 make_pf(const float* p8, int lg, int lc)
{
    union { f16x4 h; unsigned u[2]; } P0, P1;
#pragma unroll
    for (int v = 0; v < 4; ++v) {
        P0.h[v] = (_Float16)p8[v];
        P1.h[v] = (_Float16)p8[4 + v];
    }
    const int sA = (((2 * lg) & 3) << 4) + lc;
    const int sB = (((2 * lg + 1) & 3) << 4) + lc;
    const unsigned t00 = __shfl(P0.u[0], sA), t01 = __shfl(P0.u[1], sA);
    const unsigned t10 = __shfl(P1.u[0], sA), t11 = __shfl(P1.u[1], sA);
    const unsigned u00 = __shfl(P0.u[0], sB), u01 = __shfl(P0.u[1], sB);
    const unsigned u10 = __shfl(P1.u[0], sB), u11 = __shfl(P1.u[1], sB);
    const bool hi = (lg & 2) != 0;
    union { unsigned u[4]; f16x8 v; } PF;
    PF.u[0] = hi ? t10 : t00;
    PF.u[1] = hi ? t11 : t01;
    PF.u[2] = hi ? u10 : u00;
    PF.u[3] = hi ? u11 : u01;
    return PF.v;
}

// ---------------------------------------------------------------------------
// Kernel 2: fused flash attention (Z = X*P^T) + split-K merge + Wv + residual.
// Block = 512 thr = 8 waves; block owns (b, 16 queries); wave w owns keys
// [512w, 512w+512) in 8 steps of 64 keys (one softmax update per step,
// deferred-max THR=8).  Main loop barrier-free / LDS-free (verified path).
// Epilogue: LDS merge -> normalized zm[c'][q]; out = x + g * (Wv . zm).
// ---------------------------------------------------------------------------
__global__ __launch_bounds__(512) void attn_kernel(
    const _Float16* __restrict__ qh, const _Float16* __restrict__ kh,
    const _Float16* __restrict__ xp, const float* __restrict__ x,
    const float* __restrict__ Wv, const float* __restrict__ gamma,
    float* __restrict__ out)
{
    const int tid = (int)threadIdx.x;
    const int wid = tid >> 6;                      // 0..7 = K-split slice
    const int lane = tid & 63;
    const int lg = lane >> 4;                      // 0..3
    const int lc = lane & 15;                      // 0..15
    const int qi = (int)blockIdx.x & 255;
    const int b  = (int)blockIdx.x >> 8;
    const int q0 = qi * 16;

    __shared__ float sm_acc[8 * 64 * 17];          // 34816 B (stride-17 pad)
    __shared__ float sm_m[8][16];
    __shared__ float sm_l[8][16];
    __shared__ float zm[64][16];

    const f16x8 zf = {};
    const f32x4 z4 = {};

    f16x8 qfrag = zf;
    if (lg == 0)
        qfrag = *(const f16x8*)(qh + (size_t)(b * NN + q0 + lc) * 8);

    float m = -1e30f, l = 0.f;
    f32x4 acc0 = z4, acc1 = z4, acc2 = z4, acc3 = z4;

    const _Float16* khb = kh + (size_t)b * NN * 8;
    const _Float16* xpb = xp + (size_t)b * 512 * CC * 8;
    const int kbase = wid * 512;

#pragma unroll 2
    for (int ch = 0; ch < 8; ++ch) {
        const int k0 = kbase + ch * 64;

        // QK^T: D[k][q] for 4 k-tiles of 16 (64 keys)
        f16x8 kf0 = zf, kf1 = zf, kf2 = zf, kf3 = zf;
        if (lg == 0) {
            kf0 = *(const f16x8*)(khb + (size_t)(k0 + lc) * 8);
            kf1 = *(const f16x8*)(khb + (size_t)(k0 + 16 + lc) * 8);
            kf2 = *(const f16x8*)(khb + (size_t)(k0 + 32 + lc) * 8);
            kf3 = *(const f16x8*)(khb + (size_t)(k0 + 48 + lc) * 8);
        }
        f32x4 s0 = __builtin_amdgcn_mfma_f32_16x16x32_f16(kf0, qfrag, z4, 0, 0, 0);
        f32x4 s1 = __builtin_amdgcn_mfma_f32_16x16x32_f16(kf1, qfrag, z4, 0, 0, 0);
        f32x4 s2 = __builtin_amdgcn_mfma_f32_16x16x32_f16(kf2, qfrag, z4, 0, 0, 0);
        f32x4 s3 = __builtin_amdgcn_mfma_f32_16x16x32_f16(kf3, qfrag, z4, 0, 0, 0);

        // step max for my q (= lc); k-rows live across lg -> xor 16, 32
        float cm = fmaxf(
            fmaxf(fmaxf(fmaxf(s0[0], s0[1]), fmaxf(s0[2], s0[3])),
                  fmaxf(fmaxf(s1[0], s1[1]), fmaxf(s1[2], s1[3]))),
            fmaxf(fmaxf(fmaxf(s2[0], s2[1]), fmaxf(s2[2], s2[3])),
                  fmaxf(fmaxf(s3[0], s3[1]), fmaxf(s3[2], s3[3]))));
        cm = fmaxf(cm, __shfl_xor(cm, 16));
        cm = fmaxf(cm, __shfl_xor(cm, 32));

        if (!__all(cm <= m + DEFER_THR)) {         // deferred-max rescale
            const float mnew = fmaxf(m, cm);
            const float alpha = __expf(m - mnew);
            m = mnew;
            l *= alpha;
            acc0 *= alpha; acc1 *= alpha; acc2 *= alpha; acc3 *= alpha;
        }

        float pr[16];
        float ls = 0.f;
#pragma unroll
        for (int v = 0; v < 4; ++v) { pr[v]      = __expf(s0[v] - m); ls += pr[v]; }
#pragma unroll
        for (int v = 0; v < 4; ++v) { pr[4 + v]  = __expf(s1[v] - m); ls += pr[4 + v]; }
#pragma unroll
        for (int v = 0; v < 4; ++v) { pr[8 + v]  = __expf(s2[v] - m); ls += pr[8 + v]; }
#pragma unroll
        for (int v = 0; v < 4; ++v) { pr[12 + v] = __expf(s3[v] - m); ls += pr[12 + v]; }
        ls += __shfl_xor(ls, 16);
        ls += __shfl_xor(ls, 32);
        l += ls;

        // half 0: keys [k0, k0+32)
        {
            const f16x8 PF = make_pf(pr, lg, lc);
            const _Float16* vg = xpb + (size_t)((k0 >> 3) + lg) * CC * 8;
            f16x8 v0 = *(const f16x8*)(vg + (0 * 16 + lc) * 8);
            f16x8 v1 = *(const f16x8*)(vg + (1 * 16 + lc) * 8);
            f16x8 v2 = *(const f16x8*)(vg + (2 * 16 + lc) * 8);
            f16x8 v3 = *(const f16x8*)(vg + (3 * 16 + lc) * 8);
            acc0 = __builtin_amdgcn_mfma_f32_16x16x32_f16(v0, PF, acc0, 0, 0, 0);
            acc1 = __builtin_amdgcn_mfma_f32_16x16x32_f16(v1, PF, acc1, 0, 0, 0);
            acc2 = __builtin_amdgcn_mfma_f32_16x16x32_f16(v2, PF, acc2, 0, 0, 0);
            acc3 = __builtin_amdgcn_mfma_f32_16x16x32_f16(v3, PF, acc3, 0, 0, 0);
        }
        // half 1: keys [k0+32, k0+64)
        {
            const f16x8 PF = make_pf(pr + 8, lg, lc);
            const _Float16* vg = xpb + (size_t)((k0 >> 3) + 4 + lg) * CC * 8;
            f16x8 v0 = *(const f16x8*)(vg + (0 * 16 + lc) * 8);
            f16x8 v1 = *(const f16x8*)(vg + (1 * 16 + lc) * 8);
            f16x8 v2 = *(const f16x8*)(vg + (2 * 16 + lc) * 8);
            f16x8 v3 = *(const f16x8*)(vg + (3 * 16 + lc) * 8);
            acc0 = __builtin_amdgcn_mfma_f32_16x16x32_f16(v0, PF, acc0, 0, 0, 0);
            acc1 = __builtin_amdgcn_mfma_f32_16x16x32_f16(v1, PF, acc1, 0, 0, 0);
            acc2 = __builtin_amdgcn_mfma_f32_16x16x32_f16(v2, PF, acc2, 0, 0, 0);
            acc3 = __builtin_amdgcn_mfma_f32_16x16x32_f16(v3, PF, acc3, 0, 0, 0);
        }
    }

    // ---- per-wave partials -> LDS ----
    if (lane < 16) { sm_m[wid][lc] = m; sm_l[wid][lc] = l; }
    {
        float* sa = sm_acc + (size_t)wid * 64 * 17 + lc;
#pragma unroll
        for (int v = 0; v < 4; ++v) {
            sa[(0 * 16 + lg * 4 + v) * 17] = acc0[v];
            sa[(1 * 16 + lg * 4 + v) * 17] = acc1[v];
            sa[(2 * 16 + lg * 4 + v) * 17] = acc2[v];
            sa[(3 * 16 + lg * 4 + v) * 17] = acc3[v];
        }
    }
    __syncthreads();

    // ---- 8-way merge -> normalized zm[c'][q] ----
    {
        const int c = tid >> 3;                    // 0..63
        const int q2 = (tid & 7) * 2;
#pragma unroll
        for (int dq = 0; dq < 2; ++dq) {
            const int q = q2 + dq;
            float M = sm_m[0][q];
#pragma unroll
            for (int w = 1; w < 8; ++w) M = fmaxf(M, sm_m[w][q]);
            float L = 0.f, O = 0.f;
#pragma unroll
            for (int w = 0; w < 8; ++w) {
                const float e = __expf(sm_m[w][q] - M);
                L = fmaf(sm_l[w][q], e, L);
                O = fmaf(sm_acc[(w * 64 + c) * 17 + q], e, O);
            }
            zm[c][q] = O / L;
        }
    }
    __syncthreads();

    // ---- Wv epilogue + residual: out[c][q] = x + g * (Wv . zm[:,q]) ----
    {
        const int c = tid >> 3;                    // 0..63
        const int q2 = (tid & 7) * 2;
        const float* wr = Wv + c * 64;
        float o0 = 0.f, o1 = 0.f;
#pragma unroll
        for (int cc = 0; cc < 64; ++cc) {
            const float wv = wr[cc];
            o0 = fmaf(wv, zm[cc][q2],     o0);
            o1 = fmaf(wv, zm[cc][q2 + 1], o1);
        }
        const float g = gamma[0];
        const size_t oi = (size_t)b * CC * NN + (size_t)c * NN + q0 + q2;
        out[oi]     = fmaf(g, o0, x[oi]);
        out[oi + 1] = fmaf(g, o1, x[oi + 1]);
    }
}

// ---------------------------------------------------------------------------
extern "C" void kernel_launch(void* const* d_in, const int* in_sizes, int n_in,
                              void* d_out, int out_size, void* d_ws, size_t ws_size,
                              hipStream_t stream)
{
    const float* x     = (const float*)d_in[0];
    const float* Wq    = (const float*)d_in[1];
    const float* Wk    = (const float*)d_in[2];
    const float* Wv    = (const float*)d_in[3];
    const float* gamma = (const float*)d_in[4];
    float* out = (float*)d_out;

    // ws layout: qh 128K | kh 128K | xp 1M
    char* ws = (char*)d_ws;
    _Float16* qh = (_Float16*)ws;
    _Float16* kh = qh + (size_t)BB * NN * 8;
    _Float16* xp = kh + (size_t)BB * NN * 8;

    hipLaunchKernelGGL(proj_kernel, dim3(320), dim3(256), 0, stream,
                       x, Wq, Wk, qh, kh, xp);
    hipLaunchKernelGGL(attn_kernel, dim3(BB * 256), dim3(512), 0, stream,
                       qh, kh, xp, x, Wv, gamma, out);
}